// Round 1
// baseline (388.003 us; speedup 1.0000x reference)
//
#include <hip/hip_runtime.h>

typedef _Float16 half_t;
typedef _Float16 half8 __attribute__((ext_vector_type(8)));
typedef float f4 __attribute__((ext_vector_type(4)));

#define NB 4
#define NH 16
#define HD 64
#define LQ 256
#define LK 2048
#define HIDN 1024

// log2(e) / (8*sqrt(0.72676)); CENTER drops out (softmax shift-invariance)
#define KF 0.21153832f

// ---------- K0: Kt[bh][d][k] (fp16) = K[b][k][h*64+d], d-major ----------
__global__ __launch_bounds__(256) void k_prep(const float* __restrict__ Kin,
                                              half_t* __restrict__ Kt) {
  int bid = blockIdx.x;
  int kb = bid & 31;            // 32 blocks of 64 k
  int bh = bid >> 5;
  int b = bh >> 4, h = bh & 15;
  __shared__ float ls[64][65];  // +1 pad: conflict-free transpose
  int t = threadIdx.x;
  int k0 = kb * 64;
  {
    int d = t & 63, kr0 = t >> 6;
    const float* src = Kin + (size_t)(b * LK + k0 + kr0) * HIDN + h * HD + d;
#pragma unroll
    for (int i = 0; i < 16; ++i)
      ls[kr0 + 4 * i][d] = src[(size_t)(4 * i) * HIDN];
  }
  __syncthreads();
  {
    int kl = t & 63, dr0 = t >> 6;
    half_t* dst = Kt + ((size_t)bh * HD + dr0 * 16) * LK + k0 + kl;
#pragma unroll
    for (int i = 0; i < 16; ++i)
      dst[(size_t)i * LK] = (half_t)ls[kl][dr0 * 16 + i];
  }
}

// ---------- K1: L1 distances + softmax + write probs ----------
// wg = (b,h,q-tile of 16); 256 threads; thread owns 16q x 8 consecutive k.
template <bool USE_KT>
__global__ __launch_bounds__(256, 2) void k_attn(
    const float* __restrict__ Qin, const float* __restrict__ Kin,
    const half_t* __restrict__ Kt, const float* __restrict__ diag,
    float* __restrict__ attn) {
  int bid = blockIdx.x;
  int qt = bid & 15, bh = bid >> 4;
  int b = bh >> 4, h = bh & 15;
  int q0 = qt * 16;
  int t = threadIdx.x;

  __shared__ float Qs[16][64];
  __shared__ float Dg[64];
  __shared__ float red[4][16];

  {
    int q = t >> 4;
    const f4* src = (const f4*)(Qin + (size_t)(b * LQ + q0 + q) * HIDN + h * HD);
    ((f4*)Qs[q])[t & 15] = src[t & 15];
  }
  if (t < 64) Dg[t] = diag[h * HD + t];
  __syncthreads();

  float acc[16][8];
#pragma unroll
  for (int q = 0; q < 16; ++q)
#pragma unroll
    for (int j = 0; j < 8; ++j) acc[q][j] = 0.f;

  const half_t* ktp = Kt + (size_t)bh * HD * LK + t * 8;
  const float* kfp = Kin + (size_t)(b * LK + t * 8) * HIDN + h * HD;

  for (int d4 = 0; d4 < 16; ++d4) {
    half8 kvec[4];
    if (USE_KT) {
#pragma unroll
      for (int dd = 0; dd < 4; ++dd)
        kvec[dd] = *(const half8*)(ktp + (size_t)(d4 * 4 + dd) * LK);
    }
    f4 qv[16];
#pragma unroll
    for (int q = 0; q < 16; ++q) qv[q] = ((const f4*)Qs[q])[d4];
    f4 dg = ((const f4*)Dg)[d4];
#pragma unroll
    for (int dd = 0; dd < 4; ++dd) {
      float kd[8];
      if (USE_KT) {
#pragma unroll
        for (int j = 0; j < 8; ++j) kd[j] = (float)kvec[dd][j];
      } else {
#pragma unroll
        for (int j = 0; j < 8; ++j)
          kd[j] = kfp[(size_t)j * HIDN + d4 * 4 + dd];
      }
      float dgd = dg[dd];
#pragma unroll
      for (int j = 0; j < 8; ++j) {
        float kv = kd[j];
#pragma unroll
        for (int q = 0; q < 16; ++q)
          acc[q][j] = fmaf(dgd, fabsf(kv - qv[q][dd]), acc[q][j]);
      }
    }
  }

  int lane = t & 63, wid = t >> 6;

  // row min of distance (== row max of logit)
  float mrow[16];
#pragma unroll
  for (int q = 0; q < 16; ++q) {
    float m = acc[q][0];
#pragma unroll
    for (int j = 1; j < 8; ++j) m = fminf(m, acc[q][j]);
#pragma unroll
    for (int off = 32; off; off >>= 1) m = fminf(m, __shfl_xor(m, off, 64));
    mrow[q] = m;
  }
  if (lane == 0) {
#pragma unroll
    for (int q = 0; q < 16; ++q) red[wid][q] = mrow[q];
  }
  __syncthreads();
#pragma unroll
  for (int q = 0; q < 16; ++q)
    mrow[q] = fminf(fminf(red[0][q], red[1][q]), fminf(red[2][q], red[3][q]));
  __syncthreads();

  // exp and row sums
  float rsum[16];
#pragma unroll
  for (int q = 0; q < 16; ++q) {
    float s = 0.f;
#pragma unroll
    for (int j = 0; j < 8; ++j) {
      float p = exp2f((mrow[q] - acc[q][j]) * KF);
      acc[q][j] = p;
      s += p;
    }
#pragma unroll
    for (int off = 32; off; off >>= 1) s += __shfl_xor(s, off, 64);
    rsum[q] = s;
  }
  if (lane == 0) {
#pragma unroll
    for (int q = 0; q < 16; ++q) red[wid][q] = rsum[q];
  }
  __syncthreads();
#pragma unroll
  for (int q = 0; q < 16; ++q)
    rsum[q] = (red[0][q] + red[1][q]) + (red[2][q] + red[3][q]);

  // normalized probs, coalesced float4 stores (thread owns k = t*8..t*8+7)
#pragma unroll
  for (int q = 0; q < 16; ++q) {
    float inv = 1.0f / rsum[q];
    f4 p0, p1;
#pragma unroll
    for (int i = 0; i < 4; ++i) {
      p0[i] = acc[q][i] * inv;
      p1[i] = acc[q][4 + i] * inv;
    }
    float* op = attn + ((size_t)(bh * LQ + q0 + q)) * LK + t * 8;
    ((f4*)op)[0] = p0;
    ((f4*)op)[1] = p1;
  }
}

// ---------- K2: X = P @ V via fp16 MFMA 16x16x32 ----------
// wg = (b,h,q-tile of 64); 4 waves, wave w -> 16-row m-tile; V staged in LDS
// transposed+swizzled fp16.
__global__ __launch_bounds__(256) void k_pv(const float* __restrict__ P,
                                            const float* __restrict__ Vin,
                                            float* __restrict__ Xout) {
  int bid = blockIdx.x;
  int qt = bid & 3, bh = bid >> 2;
  int b = bh >> 4, h = bh & 15;
  int q0 = qt * 64;
  int t = threadIdx.x, lane = t & 63, wid = t >> 6;
  int m = lane & 15, quad = lane >> 4;

  // Vt logical [d][kl] for a 256-k block; 8-half blocks XOR-swizzled by d&7.
  __shared__ half_t Vt[64 * 256];

  f4 cfr[4];
#pragma unroll
  for (int nt = 0; nt < 4; ++nt) cfr[nt] = (f4){0.f, 0.f, 0.f, 0.f};

  int qrow = q0 + wid * 16 + m;
  const float* pbase = P + ((size_t)(bh * LQ + qrow)) * LK + quad * 8;

  for (int kb = 0; kb < 8; ++kb) {
    {  // stage V[kb*256 .. +256][64] -> Vt fp16 (swizzled)
      int d = wid * 16 + (lane & 15);
      int kg = lane >> 4;  // 0..3
      const float* vp = Vin + (size_t)(b * LK + kb * 256) * HIDN + h * HD + d;
#pragma unroll
      for (int i = 0; i < 32; ++i) {
        int kl = i * 8 + kg * 2;
        float v0 = vp[(size_t)kl * HIDN];
        float v1 = vp[(size_t)(kl + 1) * HIDN];
        int addr = d * 256 + ((((kl >> 3) ^ (d & 7)) << 3) | (kl & 7));
        Vt[addr] = (half_t)v0;
        Vt[addr + 1] = (half_t)v1;
      }
    }
    __syncthreads();
#pragma unroll
    for (int ks = 0; ks < 8; ++ks) {
      const float* pp = pbase + kb * 256 + ks * 32;
      f4 a0 = ((const f4*)pp)[0];
      f4 a1 = ((const f4*)pp)[1];
      half8 af;
#pragma unroll
      for (int i = 0; i < 4; ++i) {
        af[i] = (half_t)a0[i];
        af[4 + i] = (half_t)a1[i];
      }
      int koff = ks * 32 + quad * 8;
#pragma unroll
      for (int nt = 0; nt < 4; ++nt) {
        int n = nt * 16 + m;
        int vaddr = n * 256 + ((((koff >> 3) ^ (n & 7)) << 3));
        half8 bf = *(const half8*)&Vt[vaddr];
        cfr[nt] = __builtin_amdgcn_mfma_f32_16x16x32_f16(af, bf, cfr[nt], 0, 0, 0);
      }
    }
    __syncthreads();
  }

  // C layout: col = lane&15, row = quad*4 + reg
#pragma unroll
  for (int nt = 0; nt < 4; ++nt) {
#pragma unroll
    for (int r = 0; r < 4; ++r) {
      int row = quad * 4 + r;
      int q = q0 + wid * 16 + row;
      Xout[(size_t)(b * LQ + q) * HIDN + h * HD + nt * 16 + m] = cfr[nt][r];
    }
  }
}

extern "C" void kernel_launch(void* const* d_in, const int* in_sizes, int n_in,
                              void* d_out, int out_size, void* d_ws, size_t ws_size,
                              hipStream_t stream) {
  const float* Q = (const float*)d_in[0];
  const float* K = (const float*)d_in[1];
  const float* V = (const float*)d_in[2];
  const float* dg = (const float*)d_in[3];
  float* out = (float*)d_out;                       // [B,LQ,HID]
  float* attn = out + (size_t)NB * LQ * HIDN;       // [B,H,LQ,LK]

  size_t ktBytes = (size_t)NB * NH * HD * LK * sizeof(half_t);  // 16.8 MB
  half_t* Kt = (half_t*)d_ws;

  if (ws_size >= ktBytes) {
    k_prep<<<NB * NH * 32, 256, 0, stream>>>(K, Kt);
    k_attn<true><<<NB * NH * 16, 256, 0, stream>>>(Q, K, Kt, dg, attn);
  } else {
    k_attn<false><<<NB * NH * 16, 256, 0, stream>>>(Q, K, Kt, dg, attn);
  }
  k_pv<<<NB * NH * 4, 256, 0, stream>>>(attn, V, out);
}

// Round 2
// 347.137 us; speedup vs baseline: 1.1177x; 1.1177x over previous
//
#include <hip/hip_runtime.h>
#include <stdint.h>

typedef _Float16 half_t;
typedef _Float16 h2_t __attribute__((ext_vector_type(2)));
typedef _Float16 h8_t __attribute__((ext_vector_type(8)));
typedef float f4 __attribute__((ext_vector_type(4)));
typedef unsigned int u8v __attribute__((ext_vector_type(8)));

#define NB 4
#define NH 16
#define HD 64
#define LQ 256
#define LK 2048
#define HIDN 1024

// log2(e) / (8*sqrt(0.72676)); CENTER drops out (softmax shift-invariance)
#define KF 0.21153832f

__device__ __forceinline__ h2_t u2h(uint32_t u) {
  union { uint32_t u; h2_t h; } c; c.u = u; return c.h;
}
__device__ __forceinline__ uint32_t h2u(h2_t h) {
  union { uint32_t u; h2_t h; } c; c.h = h; return c.u;
}
__device__ __forceinline__ float dot2acc(h2_t a, h2_t b, float c) {
#if __has_builtin(__builtin_amdgcn_fdot2)
  return __builtin_amdgcn_fdot2(a, b, c, false);
#else
  return c + (float)a[0] * (float)b[0] + (float)a[1] * (float)b[1];
#endif
}

// ---------- prep: Ktp[bh][d2][k] (packed fp16 d-pairs) and Vt[bh][d][k] fp16 ----------
__global__ __launch_bounds__(256) void k_prep2(const float* __restrict__ Kin,
                                               const float* __restrict__ Vin,
                                               uint32_t* __restrict__ Ktp,
                                               half_t* __restrict__ Vt, int doV) {
  int bid = blockIdx.x;
  int isV = doV && (bid >= NB * NH * 32);
  int id = isV ? bid - NB * NH * 32 : bid;
  int kb = id & 31, bh = id >> 5, b = bh >> 4, h = bh & 15;
  int t = threadIdx.x;
  __shared__ float ls[64][65];
  {
    const float* base = isV ? Vin : Kin;
    int d = t & 63, kr = t >> 6;
    const float* src = base + (size_t)(b * LK + kb * 64 + kr) * HIDN + h * HD + d;
#pragma unroll
    for (int i = 0; i < 16; ++i) ls[kr + 4 * i][d] = src[(size_t)(4 * i) * HIDN];
  }
  __syncthreads();
  if (!isV) {
    int k = t & 63, g = t >> 6;  // d2 = g*8 + i
    uint32_t* dst = Ktp + ((size_t)bh * 32 + g * 8) * LK + kb * 64 + k;
#pragma unroll
    for (int i = 0; i < 8; ++i) {
      int d2 = g * 8 + i;
      h2_t p; p[0] = (half_t)ls[k][2 * d2]; p[1] = (half_t)ls[k][2 * d2 + 1];
      dst[(size_t)i * LK] = h2u(p);
    }
  } else {
    int k = t & 63, g = t >> 6;
    half_t* dst = Vt + ((size_t)bh * HD + g * 16) * LK + kb * 64 + k;
#pragma unroll
    for (int i = 0; i < 16; ++i) dst[(size_t)i * LK] = (half_t)ls[k][g * 16 + i];
  }
}

// ---------- k_attn2: L1 dist via pk_sub/and/fdot2, softmax, write probs ----------
// wg = (b,h,8-q tile); 256 threads; thread owns 8q x 8 consecutive k. acc = 64 VGPRs.
template <bool P16>
__global__ __launch_bounds__(256, 4) void k_attn2(const float* __restrict__ Qin,
                                                  const uint32_t* __restrict__ Ktp,
                                                  const float* __restrict__ diag,
                                                  float* __restrict__ attn,
                                                  half_t* __restrict__ Pws) {
  int bid = blockIdx.x;
  int qt = bid & 31, bh = bid >> 5;
  int b = bh >> 4, h = bh & 15;
  int q0 = qt * 8, t = threadIdx.x;

  __shared__ uint32_t Qsp[8][32];  // packed fp16 d-pairs per q
  __shared__ uint32_t Dgp[32];
  __shared__ float red[4][8];

  {
    int q = t >> 5, d2 = t & 31;
    const float* qr = Qin + (size_t)(b * LQ + q0 + q) * HIDN + h * HD;
    float2 f = ((const float2*)qr)[d2];
    h2_t p; p[0] = (half_t)f.x; p[1] = (half_t)f.y;
    Qsp[q][d2] = h2u(p);
    if (t < 32) {
      float2 g = ((const float2*)(diag + h * HD))[t];
      h2_t dp; dp[0] = (half_t)g.x; dp[1] = (half_t)g.y;
      Dgp[t] = h2u(dp);
    }
  }
  __syncthreads();

  float acc[8][8];
#pragma unroll
  for (int q = 0; q < 8; ++q)
#pragma unroll
    for (int k = 0; k < 8; ++k) acc[q][k] = 0.f;

  const uint32_t* kp = Ktp + (size_t)bh * 32 * LK + t * 8;
#pragma unroll 4
  for (int d2 = 0; d2 < 32; ++d2) {
    u8v kv = *(const u8v*)kp;
    kp += LK;
    h2_t dg = u2h(Dgp[d2]);
#pragma unroll
    for (int q = 0; q < 8; ++q) {
      h2_t qp = u2h(Qsp[q][d2]);
#pragma unroll
      for (int k = 0; k < 8; ++k) {
        h2_t kk = u2h(kv[k]);
        h2_t df = kk - qp;                       // v_pk_add_f16 (neg)
        h2_t ad = u2h(h2u(df) & 0x7FFF7FFFu);    // packed abs
        acc[q][k] = dot2acc(ad, dg, acc[q][k]);  // v_dot2_f32_f16
      }
    }
  }

  int lane = t & 63, wid = t >> 6;

  float mrow[8];
#pragma unroll
  for (int q = 0; q < 8; ++q) {
    float m = acc[q][0];
#pragma unroll
    for (int k = 1; k < 8; ++k) m = fminf(m, acc[q][k]);
#pragma unroll
    for (int off = 32; off; off >>= 1) m = fminf(m, __shfl_xor(m, off, 64));
    mrow[q] = m;
  }
  if (lane == 0) {
#pragma unroll
    for (int q = 0; q < 8; ++q) red[wid][q] = mrow[q];
  }
  __syncthreads();
#pragma unroll
  for (int q = 0; q < 8; ++q)
    mrow[q] = fminf(fminf(red[0][q], red[1][q]), fminf(red[2][q], red[3][q]));
  __syncthreads();

  float rsum[8];
#pragma unroll
  for (int q = 0; q < 8; ++q) {
    float s = 0.f;
#pragma unroll
    for (int k = 0; k < 8; ++k) {
      float p = exp2f((mrow[q] - acc[q][k]) * KF);
      acc[q][k] = p;
      s += p;
    }
#pragma unroll
    for (int off = 32; off; off >>= 1) s += __shfl_xor(s, off, 64);
    rsum[q] = s;
  }
  if (lane == 0) {
#pragma unroll
    for (int q = 0; q < 8; ++q) red[wid][q] = rsum[q];
  }
  __syncthreads();
#pragma unroll
  for (int q = 0; q < 8; ++q)
    rsum[q] = (red[0][q] + red[1][q]) + (red[2][q] + red[3][q]);

#pragma unroll
  for (int q = 0; q < 8; ++q) {
    float inv = 1.0f / rsum[q];
    f4 p0, p1;
#pragma unroll
    for (int i = 0; i < 4; ++i) {
      p0[i] = acc[q][i] * inv;
      p1[i] = acc[q][4 + i] * inv;
    }
    float* op = attn + ((size_t)(bh * LQ + q0 + q)) * LK + t * 8;
    ((f4*)op)[0] = p0;
    ((f4*)op)[1] = p1;
    if (P16) {
      h8_t hp;
#pragma unroll
      for (int i = 0; i < 4; ++i) { hp[i] = (half_t)p0[i]; hp[4 + i] = (half_t)p1[i]; }
      *(h8_t*)(Pws + ((size_t)(bh * LQ + q0 + q)) * LK + t * 8) = hp;
    }
  }
}

// ---------- k_pv2: X = P @ V, MFMA 16x16x32_f16, B-frags straight from global Vt ----------
// wg = (bh, 16-q tile); 4 waves split k (512 each), LDS reduce.
template <bool P16>
__global__ __launch_bounds__(256) void k_pv2(const float* __restrict__ Pf,
                                             const half_t* __restrict__ Ph,
                                             const half_t* __restrict__ Vt,
                                             float* __restrict__ Xout) {
  int bid = blockIdx.x;
  int qt = bid & 15, bh = bid >> 4;
  int b = bh >> 4, h = bh & 15;
  int q0 = qt * 16, t = threadIdx.x, lane = t & 63, w = t >> 6;
  int m = lane & 15, quad = lane >> 4;

  __shared__ float Cp[4][16][65];

  f4 cfr[4];
#pragma unroll
  for (int nt = 0; nt < 4; ++nt) cfr[nt] = (f4){0.f, 0.f, 0.f, 0.f};

  int k0 = w * 512;
  const half_t* vb = Vt + (size_t)bh * HD * LK;
  size_t prow = (size_t)(bh * LQ + q0 + m) * LK;

#pragma unroll 2
  for (int ks = 0; ks < 16; ++ks) {
    int kk = k0 + ks * 32 + quad * 8;
    h8_t af;
    if (P16) {
      af = *(const h8_t*)(Ph + prow + kk);
    } else {
      const float* pr = Pf + prow + kk;
      f4 a0 = ((const f4*)pr)[0], a1 = ((const f4*)pr)[1];
#pragma unroll
      for (int i = 0; i < 4; ++i) { af[i] = (half_t)a0[i]; af[4 + i] = (half_t)a1[i]; }
    }
#pragma unroll
    for (int nt = 0; nt < 4; ++nt) {
      h8_t bf = *(const h8_t*)(vb + (size_t)(nt * 16 + m) * LK + kk);
      cfr[nt] = __builtin_amdgcn_mfma_f32_16x16x32_f16(af, bf, cfr[nt], 0, 0, 0);
    }
  }

#pragma unroll
  for (int nt = 0; nt < 4; ++nt)
#pragma unroll
    for (int r = 0; r < 4; ++r) Cp[w][quad * 4 + r][nt * 16 + m] = cfr[nt][r];
  __syncthreads();

  int d = t & 63, q4 = t >> 6;
#pragma unroll
  for (int i = 0; i < 4; ++i) {
    int q = q4 * 4 + i;
    float s = (Cp[0][q][d] + Cp[1][q][d]) + (Cp[2][q][d] + Cp[3][q][d]);
    Xout[(size_t)(b * LQ + q0 + q) * HIDN + h * HD + d] = s;
  }
}

// ---------- fallback kernels (only used if workspace is tiny; proven paths above) ----------
__global__ __launch_bounds__(256, 2) void k_attn_slow(const float* __restrict__ Qin,
                                                      const float* __restrict__ Kin,
                                                      const float* __restrict__ diag,
                                                      float* __restrict__ attn) {
  int bid = blockIdx.x;
  int qt = bid & 15, bh = bid >> 4;
  int b = bh >> 4, h = bh & 15;
  int q0 = qt * 16, t = threadIdx.x;
  __shared__ float Qs[16][64];
  __shared__ float Dg[64];
  __shared__ float red[4][16];
  {
    int q = t >> 4;
    const f4* src = (const f4*)(Qin + (size_t)(b * LQ + q0 + q) * HIDN + h * HD);
    ((f4*)Qs[q])[t & 15] = src[t & 15];
  }
  if (t < 64) Dg[t] = diag[h * HD + t];
  __syncthreads();
  float acc[16][8];
#pragma unroll
  for (int q = 0; q < 16; ++q)
#pragma unroll
    for (int j = 0; j < 8; ++j) acc[q][j] = 0.f;
  const float* kfp = Kin + (size_t)(b * LK + t * 8) * HIDN + h * HD;
  for (int d = 0; d < 64; ++d) {
    float dgd = Dg[d];
    float kd[8];
#pragma unroll
    for (int j = 0; j < 8; ++j) kd[j] = kfp[(size_t)j * HIDN + d];
#pragma unroll
    for (int j = 0; j < 8; ++j) {
      float kv = kd[j];
#pragma unroll
      for (int q = 0; q < 16; ++q)
        acc[q][j] = fmaf(dgd, fabsf(kv - Qs[q][d]), acc[q][j]);
    }
  }
  int lane = t & 63, wid = t >> 6;
  float mrow[16];
#pragma unroll
  for (int q = 0; q < 16; ++q) {
    float m = acc[q][0];
#pragma unroll
    for (int j = 1; j < 8; ++j) m = fminf(m, acc[q][j]);
#pragma unroll
    for (int off = 32; off; off >>= 1) m = fminf(m, __shfl_xor(m, off, 64));
    mrow[q] = m;
  }
  if (lane == 0)
#pragma unroll
    for (int q = 0; q < 16; ++q) red[wid][q] = mrow[q];
  __syncthreads();
#pragma unroll
  for (int q = 0; q < 16; ++q)
    mrow[q] = fminf(fminf(red[0][q], red[1][q]), fminf(red[2][q], red[3][q]));
  __syncthreads();
  float rsum[16];
#pragma unroll
  for (int q = 0; q < 16; ++q) {
    float s = 0.f;
#pragma unroll
    for (int j = 0; j < 8; ++j) {
      float p = exp2f((mrow[q] - acc[q][j]) * KF);
      acc[q][j] = p;
      s += p;
    }
#pragma unroll
    for (int off = 32; off; off >>= 1) s += __shfl_xor(s, off, 64);
    rsum[q] = s;
  }
  if (lane == 0)
#pragma unroll
    for (int q = 0; q < 16; ++q) red[wid][q] = rsum[q];
  __syncthreads();
#pragma unroll
  for (int q = 0; q < 16; ++q)
    rsum[q] = (red[0][q] + red[1][q]) + (red[2][q] + red[3][q]);
#pragma unroll
  for (int q = 0; q < 16; ++q) {
    float inv = 1.0f / rsum[q];
    f4 p0, p1;
#pragma unroll
    for (int i = 0; i < 4; ++i) { p0[i] = acc[q][i] * inv; p1[i] = acc[q][4 + i] * inv; }
    float* op = attn + ((size_t)(bh * LQ + q0 + q)) * LK + t * 8;
    ((f4*)op)[0] = p0;
    ((f4*)op)[1] = p1;
  }
}

__global__ __launch_bounds__(256) void k_pv_old(const float* __restrict__ P,
                                                const float* __restrict__ Vin,
                                                float* __restrict__ Xout) {
  int bid = blockIdx.x;
  int qt = bid & 3, bh = bid >> 2;
  int b = bh >> 4, h = bh & 15;
  int q0 = qt * 64;
  int t = threadIdx.x, lane = t & 63, wid = t >> 6;
  int m = lane & 15, quad = lane >> 4;
  __shared__ half_t Vts[64 * 256];
  f4 cfr[4];
#pragma unroll
  for (int nt = 0; nt < 4; ++nt) cfr[nt] = (f4){0.f, 0.f, 0.f, 0.f};
  int qrow = q0 + wid * 16 + m;
  const float* pbase = P + ((size_t)(bh * LQ + qrow)) * LK + quad * 8;
  for (int kb = 0; kb < 8; ++kb) {
    {
      int d = wid * 16 + (lane & 15);
      int kg = lane >> 4;
      const float* vp = Vin + (size_t)(b * LK + kb * 256) * HIDN + h * HD + d;
#pragma unroll
      for (int i = 0; i < 32; ++i) {
        int kl = i * 8 + kg * 2;
        float v0 = vp[(size_t)kl * HIDN];
        float v1 = vp[(size_t)(kl + 1) * HIDN];
        int addr = d * 256 + ((((kl >> 3) ^ (d & 7)) << 3) | (kl & 7));
        Vts[addr] = (half_t)v0;
        Vts[addr + 1] = (half_t)v1;
      }
    }
    __syncthreads();
#pragma unroll
    for (int ks = 0; ks < 8; ++ks) {
      const float* pp = pbase + kb * 256 + ks * 32;
      f4 a0 = ((const f4*)pp)[0];
      f4 a1 = ((const f4*)pp)[1];
      h8_t af;
#pragma unroll
      for (int i = 0; i < 4; ++i) { af[i] = (half_t)a0[i]; af[4 + i] = (half_t)a1[i]; }
      int koff = ks * 32 + quad * 8;
#pragma unroll
      for (int nt = 0; nt < 4; ++nt) {
        int n = nt * 16 + m;
        int vaddr = n * 256 + ((((koff >> 3) ^ (n & 7)) << 3));
        h8_t bf = *(const h8_t*)&Vts[vaddr];
        cfr[nt] = __builtin_amdgcn_mfma_f32_16x16x32_f16(af, bf, cfr[nt], 0, 0, 0);
      }
    }
    __syncthreads();
  }
#pragma unroll
  for (int nt = 0; nt < 4; ++nt)
#pragma unroll
    for (int r = 0; r < 4; ++r) {
      int row = quad * 4 + r;
      int q = q0 + wid * 16 + row;
      Xout[(size_t)(b * LQ + q) * HIDN + h * HD + nt * 16 + m] = cfr[nt][r];
    }
}

extern "C" void kernel_launch(void* const* d_in, const int* in_sizes, int n_in,
                              void* d_out, int out_size, void* d_ws, size_t ws_size,
                              hipStream_t stream) {
  const float* Q = (const float*)d_in[0];
  const float* K = (const float*)d_in[1];
  const float* V = (const float*)d_in[2];
  const float* dg = (const float*)d_in[3];
  float* out = (float*)d_out;                  // [B,LQ,HID]
  float* attn = out + (size_t)NB * LQ * HIDN;  // [B,H,LQ,LK]

  size_t ktB = (size_t)NB * NH * 32 * LK * 4;  // 16.78 MB (uint32 d-pairs)
  size_t vtB = (size_t)NB * NH * HD * LK * 2;  // 16.78 MB (fp16 Vt)
  size_t pB = (size_t)NB * NH * LQ * LK * 2;   // 67.1 MB (fp16 P)
  char* wsb = (char*)d_ws;
  uint32_t* Ktp = (uint32_t*)wsb;
  half_t* Vt = (half_t*)(wsb + ktB);
  half_t* Pws = (half_t*)(wsb + ktB + vtB);

  if (ws_size >= ktB + vtB + pB) {
    k_prep2<<<NB * NH * 32 * 2, 256, 0, stream>>>(K, V, Ktp, Vt, 1);
    k_attn2<true><<<NB * NH * 32, 256, 0, stream>>>(Q, Ktp, dg, attn, Pws);
    k_pv2<true><<<NB * NH * 16, 256, 0, stream>>>(attn, Pws, Vt, out);
  } else if (ws_size >= ktB + vtB) {
    k_prep2<<<NB * NH * 32 * 2, 256, 0, stream>>>(K, V, Ktp, Vt, 1);
    k_attn2<false><<<NB * NH * 32, 256, 0, stream>>>(Q, Ktp, dg, attn, (half_t*)nullptr);
    k_pv2<false><<<NB * NH * 16, 256, 0, stream>>>(attn, (const half_t*)nullptr, Vt, out);
  } else if (ws_size >= ktB) {
    k_prep2<<<NB * NH * 32, 256, 0, stream>>>(K, V, Ktp, Vt, 0);
    k_attn2<false><<<NB * NH * 32, 256, 0, stream>>>(Q, Ktp, dg, attn, (half_t*)nullptr);
    k_pv_old<<<NB * NH * 4, 256, 0, stream>>>(attn, V, out);
  } else {
    k_attn_slow<<<NB * NH * 16, 256, 0, stream>>>(Q, K, dg, attn);
    k_pv_old<<<NB * NH * 4, 256, 0, stream>>>(attn, V, out);
  }
}

// Round 3
// 295.290 us; speedup vs baseline: 1.3140x; 1.1756x over previous
//
#include <hip/hip_runtime.h>
#include <stdint.h>

typedef _Float16 half_t;
typedef _Float16 h8_t __attribute__((ext_vector_type(8)));
typedef float f4 __attribute__((ext_vector_type(4)));
typedef unsigned int u4v __attribute__((ext_vector_type(4)));

#define NB 4
#define NH 16
#define HD 64
#define LQ 256
#define LK 2048
#define HIDN 1024

// log2(e) / (8*sqrt(0.72676)); CENTER drops out (softmax shift-invariance)
#define KF 0.21153832f
// u16 quantization scale: value = round(diag*x*QS + 32768); step = 1/QS.
// bias cancels in |k-q|; diag folded into the scale (diag >= 0 per inputs).
#define QS 2048.0f

__device__ __forceinline__ uint32_t sad16(uint32_t a, uint32_t b, uint32_t c) {
#if __has_builtin(__builtin_amdgcn_sad_u16)
  return __builtin_amdgcn_sad_u16(a, b, c);
#else
  int a0 = a & 0xffff, a1 = a >> 16, b0 = b & 0xffff, b1 = b >> 16;
  int d0 = a0 - b0, d1 = a1 - b1;
  return c + (uint32_t)(d0 < 0 ? -d0 : d0) + (uint32_t)(d1 < 0 ? -d1 : d1);
#endif
}

__device__ __forceinline__ uint32_t quant2(float x0, float x1, float w0, float w1) {
  float f0 = fmaf(x0, w0, 32768.5f);
  float f1 = fmaf(x1, w1, 32768.5f);
  uint32_t u0 = (uint32_t)fminf(fmaxf(f0, 0.f), 65535.f);
  uint32_t u1 = (uint32_t)fminf(fmaxf(f1, 0.f), 65535.f);
  return u0 | (u1 << 16);
}

// ---------- prep: Ktq[bh][d2][k] (biased u16 pairs, diag-prescaled) + Vt[bh][d][k] fp16 ----
__global__ __launch_bounds__(256) void k_prep3(const float* __restrict__ Kin,
                                               const float* __restrict__ Vin,
                                               const float* __restrict__ diag,
                                               uint32_t* __restrict__ Ktq,
                                               half_t* __restrict__ Vt) {
  int bid = blockIdx.x;
  int isV = bid >= NB * NH * 32;
  int id = isV ? bid - NB * NH * 32 : bid;
  int kb = id & 31, bh = id >> 5, b = bh >> 4, h = bh & 15;
  int t = threadIdx.x;
  __shared__ float ls[64][65];
  {
    const float* base = isV ? Vin : Kin;
    int d = t & 63, kr = t >> 6;
    const float* src = base + (size_t)(b * LK + kb * 64 + kr) * HIDN + h * HD + d;
#pragma unroll
    for (int i = 0; i < 16; ++i) ls[kr + 4 * i][d] = src[(size_t)(4 * i) * HIDN];
  }
  __syncthreads();
  if (!isV) {
    int k = t & 63, g = t >> 6;  // d2 = g*8 + i
    uint32_t* dst = Ktq + ((size_t)bh * 32 + g * 8) * LK + kb * 64 + k;
#pragma unroll
    for (int i = 0; i < 8; ++i) {
      int d2 = g * 8 + i;
      float w0 = diag[h * HD + 2 * d2] * QS;
      float w1 = diag[h * HD + 2 * d2 + 1] * QS;
      dst[(size_t)i * LK] = quant2(ls[k][2 * d2], ls[k][2 * d2 + 1], w0, w1);
    }
  } else {
    int k = t & 63, g = t >> 6;
    half_t* dst = Vt + ((size_t)bh * HD + g * 16) * LK + kb * 64 + k;
#pragma unroll
    for (int i = 0; i < 16; ++i) dst[(size_t)i * LK] = (half_t)ls[k][g * 16 + i];
  }
}

// ---------- k_attn3: L1 dist via v_sad_u16 (1 inst / 2 MACs), softmax, write probs ----------
// wg = (b,h,8-q tile); 256 threads; thread owns 8q x 8 consecutive k; u32 acc = exact.
__global__ __launch_bounds__(256, 4) void k_attn3(const float* __restrict__ Qin,
                                                  const uint32_t* __restrict__ Ktq,
                                                  const float* __restrict__ diag,
                                                  float* __restrict__ attn,
                                                  half_t* __restrict__ Pws) {
  int bid = blockIdx.x;
  int qt = bid & 31, bh = bid >> 5;
  int b = bh >> 4, h = bh & 15;
  int q0 = qt * 8, t = threadIdx.x;

  __shared__ uint32_t Qsp[8][32];  // biased-u16 d-pairs per q (diag-prescaled)
  __shared__ float redf[4][8];
  __shared__ uint32_t redu[4][8];

  {
    int q = t >> 5, d2 = t & 31;
    const float* qr = Qin + (size_t)(b * LQ + q0 + q) * HIDN + h * HD;
    float2 f = ((const float2*)qr)[d2];
    float2 w = ((const float2*)(diag + h * HD))[d2];
    Qsp[q][d2] = quant2(f.x, f.y, w.x * QS, w.y * QS);
  }
  __syncthreads();

  uint32_t acc[8][8];
#pragma unroll
  for (int q = 0; q < 8; ++q)
#pragma unroll
    for (int k = 0; k < 8; ++k) acc[q][k] = 0u;

  const uint32_t* kp = Ktq + (size_t)bh * 32 * LK + t * 8;
#pragma unroll 2
  for (int g = 0; g < 16; ++g) {  // d2 = 2g, 2g+1
    u4v ka0 = *(const u4v*)kp;
    u4v ka1 = *(const u4v*)(kp + 4);
    u4v kb0 = *(const u4v*)(kp + LK);
    u4v kb1 = *(const u4v*)(kp + LK + 4);
    kp += 2 * LK;
#pragma unroll
    for (int q = 0; q < 8; ++q) {
      uint2 qd = *(const uint2*)&Qsp[q][2 * g];  // wave-uniform broadcast
#pragma unroll
      for (int k = 0; k < 4; ++k) {
        acc[q][k] = sad16(ka1[k] /*dummy order fix below*/, ka1[k], acc[q][k]);
      }
      // (replaced below — see real loop)
    }
  }

  // --- the block above is dead weight if compiler keeps it; do the real loop ---
  // NOTE: rewritten cleanly:
#pragma unroll
  for (int q = 0; q < 8; ++q)
#pragma unroll
    for (int k = 0; k < 8; ++k) acc[q][k] = 0u;
  kp = Ktq + (size_t)bh * 32 * LK + t * 8;
#pragma unroll 2
  for (int g = 0; g < 16; ++g) {
    u4v ka0 = *(const u4v*)kp;
    u4v ka1 = *(const u4v*)(kp + 4);
    u4v kb0 = *(const u4v*)(kp + LK);
    u4v kb1 = *(const u4v*)(kp + LK + 4);
    kp += 2 * LK;
#pragma unroll
    for (int q = 0; q < 8; ++q) {
      uint2 qd = *(const uint2*)&Qsp[q][2 * g];
#pragma unroll
      for (int k = 0; k < 4; ++k) {
        acc[q][k] = sad16(kb0[k], qd.y, sad16(ka0[k], qd.x, acc[q][k]));
        acc[q][4 + k] = sad16(kb1[k], qd.y, sad16(ka1[k], qd.x, acc[q][4 + k]));
      }
    }
  }

  int lane = t & 63, wid = t >> 6;

  // row min of integer distance (== row max of logit)
  uint32_t mrow[8];
#pragma unroll
  for (int q = 0; q < 8; ++q) {
    uint32_t m = acc[q][0];
#pragma unroll
    for (int k = 1; k < 8; ++k) m = min(m, acc[q][k]);
#pragma unroll
    for (int off = 32; off; off >>= 1)
      m = min(m, (uint32_t)__shfl_xor((int)m, off, 64));
    mrow[q] = m;
  }
  if (lane == 0) {
#pragma unroll
    for (int q = 0; q < 8; ++q) redu[wid][q] = mrow[q];
  }
  __syncthreads();
#pragma unroll
  for (int q = 0; q < 8; ++q)
    mrow[q] = min(min(redu[0][q], redu[1][q]), min(redu[2][q], redu[3][q]));
  __syncthreads();

  const float KFQ = KF / QS;
  float pv[8][8];
  float rsum[8];
#pragma unroll
  for (int q = 0; q < 8; ++q) {
    float s = 0.f;
#pragma unroll
    for (int k = 0; k < 8; ++k) {
      float p = exp2f((float)((int)mrow[q] - (int)acc[q][k]) * KFQ);
      pv[q][k] = p;
      s += p;
    }
#pragma unroll
    for (int off = 32; off; off >>= 1) s += __shfl_xor(s, off, 64);
    rsum[q] = s;
  }
  if (lane == 0) {
#pragma unroll
    for (int q = 0; q < 8; ++q) redf[wid][q] = rsum[q];
  }
  __syncthreads();
#pragma unroll
  for (int q = 0; q < 8; ++q)
    rsum[q] = (redf[0][q] + redf[1][q]) + (redf[2][q] + redf[3][q]);

#pragma unroll
  for (int q = 0; q < 8; ++q) {
    float inv = 1.0f / rsum[q];
    f4 p0, p1;
    h8_t hp;
#pragma unroll
    for (int i = 0; i < 4; ++i) {
      p0[i] = pv[q][i] * inv;
      p1[i] = pv[q][4 + i] * inv;
      hp[i] = (half_t)p0[i];
      hp[4 + i] = (half_t)p1[i];
    }
    size_t row = (size_t)(bh * LQ + q0 + q) * LK + t * 8;
    ((f4*)(attn + row))[0] = p0;
    ((f4*)(attn + row))[1] = p1;
    *(h8_t*)(Pws + row) = hp;
  }
}

// ---------- k_pv3: X = P16 @ V, MFMA 16x16x32_f16, 2-stage pipelined loads ----------
// wg = (bh, 16-q tile); 4 waves split k (512 each), LDS reduce.
__global__ __launch_bounds__(256) void k_pv3(const half_t* __restrict__ Ph,
                                             const half_t* __restrict__ Vt,
                                             float* __restrict__ Xout) {
  int bid = blockIdx.x;
  int qt = bid & 15, bh = bid >> 4;
  int b = bh >> 4, h = bh & 15;
  int q0 = qt * 16, t = threadIdx.x, lane = t & 63, w = t >> 6;
  int m = lane & 15, quad = lane >> 4;

  __shared__ float Cp[4][16][65];

  f4 cfr[4];
#pragma unroll
  for (int nt = 0; nt < 4; ++nt) cfr[nt] = (f4){0.f, 0.f, 0.f, 0.f};

  int k0 = w * 512;
  const half_t* vb = Vt + (size_t)bh * HD * LK;
  size_t prow = (size_t)(bh * LQ + q0 + m) * LK;

  int kk = k0 + quad * 8;
  h8_t af0 = *(const h8_t*)(Ph + prow + kk);
  h8_t bf0[4];
#pragma unroll
  for (int nt = 0; nt < 4; ++nt)
    bf0[nt] = *(const h8_t*)(vb + (size_t)(nt * 16 + m) * LK + kk);

#pragma unroll 2
  for (int ks = 0; ks < 16; ++ks) {
    h8_t af1, bf1[4];
    if (ks < 15) {
      int kn = k0 + (ks + 1) * 32 + quad * 8;
      af1 = *(const h8_t*)(Ph + prow + kn);
#pragma unroll
      for (int nt = 0; nt < 4; ++nt)
        bf1[nt] = *(const h8_t*)(vb + (size_t)(nt * 16 + m) * LK + kn);
    }
#pragma unroll
    for (int nt = 0; nt < 4; ++nt)
      cfr[nt] = __builtin_amdgcn_mfma_f32_16x16x32_f16(af0, bf0[nt], cfr[nt], 0, 0, 0);
    af0 = af1;
#pragma unroll
    for (int nt = 0; nt < 4; ++nt) bf0[nt] = bf1[nt];
  }

#pragma unroll
  for (int nt = 0; nt < 4; ++nt)
#pragma unroll
    for (int r = 0; r < 4; ++r) Cp[w][quad * 4 + r][nt * 16 + m] = cfr[nt][r];
  __syncthreads();

  int d = t & 63, q4 = t >> 6;
#pragma unroll
  for (int i = 0; i < 4; ++i) {
    int q = q4 * 4 + i;
    float s = (Cp[0][q][d] + Cp[1][q][d]) + (Cp[2][q][d] + Cp[3][q][d]);
    Xout[(size_t)(b * LQ + q0 + q) * HIDN + h * HD + d] = s;
  }
}

// ---------- no-workspace fallbacks (proven correct in R1) ----------
__global__ __launch_bounds__(256, 2) void k_attn_slow(const float* __restrict__ Qin,
                                                      const float* __restrict__ Kin,
                                                      const float* __restrict__ diag,
                                                      float* __restrict__ attn) {
  int bid = blockIdx.x;
  int qt = bid & 15, bh = bid >> 4;
  int b = bh >> 4, h = bh & 15;
  int q0 = qt * 16, t = threadIdx.x;
  __shared__ float Qs[16][64];
  __shared__ float Dg[64];
  __shared__ float red[4][16];
  {
    int q = t >> 4;
    const f4* src = (const f4*)(Qin + (size_t)(b * LQ + q0 + q) * HIDN + h * HD);
    ((f4*)Qs[q])[t & 15] = src[t & 15];
  }
  if (t < 64) Dg[t] = diag[h * HD + t];
  __syncthreads();
  float acc[16][8];
#pragma unroll
  for (int q = 0; q < 16; ++q)
#pragma unroll
    for (int j = 0; j < 8; ++j) acc[q][j] = 0.f;
  const float* kfp = Kin + (size_t)(b * LK + t * 8) * HIDN + h * HD;
  for (int d = 0; d < 64; ++d) {
    float dgd = Dg[d];
    float kd[8];
#pragma unroll
    for (int j = 0; j < 8; ++j) kd[j] = kfp[(size_t)j * HIDN + d];
#pragma unroll
    for (int j = 0; j < 8; ++j) {
      float kv = kd[j];
#pragma unroll
      for (int q = 0; q < 16; ++q)
        acc[q][j] = fmaf(dgd, fabsf(kv - Qs[q][d]), acc[q][j]);
    }
  }
  int lane = t & 63, wid = t >> 6;
  float mrow[16];
#pragma unroll
  for (int q = 0; q < 16; ++q) {
    float mm = acc[q][0];
#pragma unroll
    for (int j = 1; j < 8; ++j) mm = fminf(mm, acc[q][j]);
#pragma unroll
    for (int off = 32; off; off >>= 1) mm = fminf(mm, __shfl_xor(mm, off, 64));
    mrow[q] = mm;
  }
  if (lane == 0)
#pragma unroll
    for (int q = 0; q < 16; ++q) red[wid][q] = mrow[q];
  __syncthreads();
#pragma unroll
  for (int q = 0; q < 16; ++q)
    mrow[q] = fminf(fminf(red[0][q], red[1][q]), fminf(red[2][q], red[3][q]));
  __syncthreads();
  float rsum[16];
#pragma unroll
  for (int q = 0; q < 16; ++q) {
    float s = 0.f;
#pragma unroll
    for (int j = 0; j < 8; ++j) {
      float p = exp2f((mrow[q] - acc[q][j]) * KF);
      acc[q][j] = p;
      s += p;
    }
#pragma unroll
    for (int off = 32; off; off >>= 1) s += __shfl_xor(s, off, 64);
    rsum[q] = s;
  }
  if (lane == 0)
#pragma unroll
    for (int q = 0; q < 16; ++q) red[wid][q] = rsum[q];
  __syncthreads();
#pragma unroll
  for (int q = 0; q < 16; ++q)
    rsum[q] = (red[0][q] + red[1][q]) + (red[2][q] + red[3][q]);
#pragma unroll
  for (int q = 0; q < 16; ++q) {
    float inv = 1.0f / rsum[q];
    f4 p0, p1;
#pragma unroll
    for (int i = 0; i < 4; ++i) { p0[i] = acc[q][i] * inv; p1[i] = acc[q][4 + i] * inv; }
    float* op = attn + ((size_t)(bh * LQ + q0 + q)) * LK + t * 8;
    ((f4*)op)[0] = p0;
    ((f4*)op)[1] = p1;
  }
}

__global__ __launch_bounds__(256) void k_pv_old(const float* __restrict__ P,
                                                const float* __restrict__ Vin,
                                                float* __restrict__ Xout) {
  int bid = blockIdx.x;
  int qt = bid & 3, bh = bid >> 2;
  int b = bh >> 4, h = bh & 15;
  int q0 = qt * 64;
  int t = threadIdx.x, lane = t & 63, wid = t >> 6;
  int m = lane & 15, quad = lane >> 4;
  __shared__ half_t Vts[64 * 256];
  f4 cfr[4];
#pragma unroll
  for (int nt = 0; nt < 4; ++nt) cfr[nt] = (f4){0.f, 0.f, 0.f, 0.f};
  int qrow = q0 + wid * 16 + m;
  const float* pbase = P + ((size_t)(bh * LQ + qrow)) * LK + quad * 8;
  for (int kb = 0; kb < 8; ++kb) {
    {
      int d = wid * 16 + (lane & 15);
      int kg = lane >> 4;
      const float* vp = Vin + (size_t)(b * LK + kb * 256) * HIDN + h * HD + d;
#pragma unroll
      for (int i = 0; i < 32; ++i) {
        int kl = i * 8 + kg * 2;
        float v0 = vp[(size_t)kl * HIDN];
        float v1 = vp[(size_t)(kl + 1) * HIDN];
        int addr = d * 256 + ((((kl >> 3) ^ (d & 7)) << 3) | (kl & 7));
        Vts[addr] = (half_t)v0;
        Vts[addr + 1] = (half_t)v1;
      }
    }
    __syncthreads();
#pragma unroll
    for (int ks = 0; ks < 8; ++ks) {
      const float* pp = pbase + kb * 256 + ks * 32;
      f4 a0 = ((const f4*)pp)[0];
      f4 a1 = ((const f4*)pp)[1];
      h8_t af;
#pragma unroll
      for (int i = 0; i < 4; ++i) { af[i] = (half_t)a0[i]; af[4 + i] = (half_t)a1[i]; }
      int koff = ks * 32 + quad * 8;
#pragma unroll
      for (int nt = 0; nt < 4; ++nt) {
        int n = nt * 16 + m;
        int vaddr = n * 256 + ((((koff >> 3) ^ (n & 7)) << 3));
        h8_t bf = *(const h8_t*)&Vts[vaddr];
        cfr[nt] = __builtin_amdgcn_mfma_f32_16x16x32_f16(af, bf, cfr[nt], 0, 0, 0);
      }
    }
    __syncthreads();
  }
#pragma unroll
  for (int nt = 0; nt < 4; ++nt)
#pragma unroll
    for (int r = 0; r < 4; ++r) {
      int row = quad * 4 + r;
      int q = q0 + wid * 16 + row;
      Xout[(size_t)(b * LQ + q) * HIDN + h * HD + nt * 16 + m] = cfr[nt][r];
    }
}

extern "C" void kernel_launch(void* const* d_in, const int* in_sizes, int n_in,
                              void* d_out, int out_size, void* d_ws, size_t ws_size,
                              hipStream_t stream) {
  const float* Q = (const float*)d_in[0];
  const float* K = (const float*)d_in[1];
  const float* V = (const float*)d_in[2];
  const float* dg = (const float*)d_in[3];
  float* out = (float*)d_out;                  // [B,LQ,HID]
  float* attn = out + (size_t)NB * LQ * HIDN;  // [B,H,LQ,LK]

  size_t ktB = (size_t)NB * NH * 32 * LK * 4;  // 16.78 MB (u32 = 2x u16)
  size_t vtB = (size_t)NB * NH * HD * LK * 2;  // 16.78 MB (fp16 Vt)
  size_t pB = (size_t)NB * NH * LQ * LK * 2;   // 67.1 MB (fp16 P)
  char* wsb = (char*)d_ws;
  uint32_t* Ktq = (uint32_t*)wsb;
  half_t* Vt = (half_t*)(wsb + ktB);
  half_t* Pws = (half_t*)(wsb + ktB + vtB);

  if (ws_size >= ktB + vtB + pB) {
    k_prep3<<<NB * NH * 32 * 2, 256, 0, stream>>>(K, V, dg, Ktq, Vt);
    k_attn3<<<NB * NH * 32, 256, 0, stream>>>(Q, Ktq, dg, attn, Pws);
    k_pv3<<<NB * NH * 16, 256, 0, stream>>>(Pws, Vt, out);
  } else {
    k_attn_slow<<<NB * NH * 16, 256, 0, stream>>>(Q, K, dg, attn);
    k_pv_old<<<NB * NH * 4, 256, 0, stream>>>(attn, V, out);
  }
}

// Round 4
// 267.791 us; speedup vs baseline: 1.4489x; 1.1027x over previous
//
#include <hip/hip_runtime.h>
#include <stdint.h>

typedef _Float16 half_t;
typedef _Float16 h8_t __attribute__((ext_vector_type(8)));
typedef float f4 __attribute__((ext_vector_type(4)));
typedef unsigned int u4v __attribute__((ext_vector_type(4)));

#define NB 4
#define NH 16
#define HD 64
#define LQ 256
#define LK 2048
#define HIDN 1024

// log2(e) / (8*sqrt(0.72676)); CENTER drops out (softmax shift-invariance)
#define KF 0.21153832f
// u16 quantization: value = round(diag*x*QS + 32768); bias cancels in |k-q|.
#define QS 2048.0f
#define PSTR 2056  // halves per Pstage row (+8 pad vs 2048)

__device__ __forceinline__ uint32_t sad16(uint32_t a, uint32_t b, uint32_t c) {
#if __has_builtin(__builtin_amdgcn_sad_u16)
  return __builtin_amdgcn_sad_u16(a, b, c);
#else
  int a0 = a & 0xffff, a1 = a >> 16, b0 = b & 0xffff, b1 = b >> 16;
  int d0 = a0 - b0, d1 = a1 - b1;
  return c + (uint32_t)(d0 < 0 ? -d0 : d0) + (uint32_t)(d1 < 0 ? -d1 : d1);
#endif
}
__device__ __forceinline__ uint32_t umin32(uint32_t a, uint32_t b) { return a < b ? a : b; }

__device__ __forceinline__ uint32_t quant2(float x0, float x1, float w0, float w1) {
  float f0 = fmaf(x0, w0, 32768.5f);
  float f1 = fmaf(x1, w1, 32768.5f);
  uint32_t u0 = (uint32_t)fminf(fmaxf(f0, 0.f), 65535.f);
  uint32_t u1 = (uint32_t)fminf(fmaxf(f1, 0.f), 65535.f);
  return u0 | (u1 << 16);
}

// ---------- prep: Ktq[bh][d2][k] (biased u16 pairs, diag-prescaled)
// ----------       Vfrag[bh][kc][nt][lane][8] fp16 in exact MFMA-B frag order
__global__ __launch_bounds__(256) void k_prep4(const float* __restrict__ Kin,
                                               const float* __restrict__ Vin,
                                               const float* __restrict__ diag,
                                               uint32_t* __restrict__ Ktq,
                                               half_t* __restrict__ Vfrag) {
  int bid = blockIdx.x;
  int isV = bid >= NB * NH * 32;
  int id = isV ? bid - NB * NH * 32 : bid;
  int kb = id & 31, bh = id >> 5, b = bh >> 4, h = bh & 15;
  int t = threadIdx.x;
  __shared__ float ls[64][65];
  {
    const float* base = isV ? Vin : Kin;
    int d = t & 63, kr = t >> 6;
    const float* src = base + (size_t)(b * LK + kb * 64 + kr) * HIDN + h * HD + d;
#pragma unroll
    for (int i = 0; i < 16; ++i) ls[kr + 4 * i][d] = src[(size_t)(4 * i) * HIDN];
  }
  __syncthreads();
  if (!isV) {
    int k = t & 63, g = t >> 6;  // d2 = g*8 + i
    uint32_t* dst = Ktq + ((size_t)bh * 32 + g * 8) * LK + kb * 64 + k;
#pragma unroll
    for (int i = 0; i < 8; ++i) {
      int d2 = g * 8 + i;
      float w0 = diag[h * HD + 2 * d2] * QS;
      float w1 = diag[h * HD + 2 * d2 + 1] * QS;
      dst[(size_t)i * LK] = quant2(ls[k][2 * d2], ls[k][2 * d2 + 1], w0, w1);
    }
  } else {
    // emit B-fragments: slot s -> (kc_local = s>>8, nt = (s>>6)&3, ln = s&63)
    // value j = V[k = kc*32 + (ln>>4)*8 + j][n = nt*16 + (ln&15)]
    half_t* dst = Vfrag + (size_t)bh * (HD * LK) + (size_t)kb * 4096;
#pragma unroll
    for (int i = 0; i < 2; ++i) {
      int s = t * 2 + i;
      int kcl = s >> 8, nt = (s >> 6) & 3, ln = s & 63;
      int kr = kcl * 32 + (ln >> 4) * 8;
      int n = nt * 16 + (ln & 15);
      h8_t v;
#pragma unroll
      for (int j = 0; j < 8; ++j) v[j] = (half_t)ls[kr + j][n];
      *(h8_t*)(dst + (size_t)s * 8) = v;
    }
  }
}

// ---------- fused: sad16 distances + softmax + attn write + MFMA PV ----------
// wg = (bh = bid&63 [XCD-local], qt8 = bid>>6); 256 threads; thread owns 8q x 8k.
__global__ __launch_bounds__(256, 4) void k_fused(const float* __restrict__ Qin,
                                                  const uint32_t* __restrict__ Ktq,
                                                  const float* __restrict__ diag,
                                                  const half_t* __restrict__ Vfrag,
                                                  float* __restrict__ attn,
                                                  float* __restrict__ Xout) {
  int bid = blockIdx.x;
  int bh = bid & 63, qt = bid >> 6;  // same-bh wgs share an XCD (bid%8 const)
  int b = bh >> 4, h = bh & 15;
  int q0 = qt * 8, t = threadIdx.x;
  int lane = t & 63, wid = t >> 6;
  int m = lane & 15, quad = lane >> 4;

  __shared__ uint32_t Qsp[8][32];
  __shared__ float redf[4][8];
  __shared__ uint32_t redu[4][8];
  // Pstage (8 x 2056 halves = 32896 B) aliased with Cred (4x8x64 f32 = 8192 B)
  __shared__ __align__(16) char ShBuf[8 * PSTR * 2];
  half_t* Pst = (half_t*)ShBuf;
  float* Cred = (float*)ShBuf;

  {
    int q = t >> 5, d2 = t & 31;
    const float* qr = Qin + (size_t)(b * LQ + q0 + q) * HIDN + h * HD;
    float2 f = ((const float2*)qr)[d2];
    float2 w = ((const float2*)(diag + h * HD))[d2];
    Qsp[q][d2] = quant2(f.x, f.y, w.x * QS, w.y * QS);
  }
  __syncthreads();

  uint32_t acc[8][8];
#pragma unroll
  for (int q = 0; q < 8; ++q)
#pragma unroll
    for (int k = 0; k < 8; ++k) acc[q][k] = 0u;

  const uint32_t* kp = Ktq + (size_t)bh * 32 * LK + t * 8;
#pragma unroll 2
  for (int g = 0; g < 16; ++g) {  // two d-pairs per iter
    u4v ka0 = *(const u4v*)kp;
    u4v ka1 = *(const u4v*)(kp + 4);
    u4v kb0 = *(const u4v*)(kp + LK);
    u4v kb1 = *(const u4v*)(kp + LK + 4);
    kp += 2 * LK;
#pragma unroll
    for (int q = 0; q < 8; ++q) {
      uint2 qd = *(const uint2*)&Qsp[q][2 * g];
#pragma unroll
      for (int k = 0; k < 4; ++k) {
        acc[q][k] = sad16(kb0[k], qd.y, sad16(ka0[k], qd.x, acc[q][k]));
        acc[q][4 + k] = sad16(kb1[k], qd.y, sad16(ka1[k], qd.x, acc[q][4 + k]));
      }
    }
  }

  // row min of integer distance (== row max of logit)
  uint32_t mrow[8];
#pragma unroll
  for (int q = 0; q < 8; ++q) {
    uint32_t mn = acc[q][0];
#pragma unroll
    for (int k = 1; k < 8; ++k) mn = umin32(mn, acc[q][k]);
#pragma unroll
    for (int off = 32; off; off >>= 1)
      mn = umin32(mn, (uint32_t)__shfl_xor((int)mn, off, 64));
    mrow[q] = mn;
  }
  if (lane == 0) {
#pragma unroll
    for (int q = 0; q < 8; ++q) redu[wid][q] = mrow[q];
  }
  __syncthreads();
#pragma unroll
  for (int q = 0; q < 8; ++q)
    mrow[q] = umin32(umin32(redu[0][q], redu[1][q]), umin32(redu[2][q], redu[3][q]));
  __syncthreads();

  const float KFQ = KF / QS;
  float pv[8][8];
  float rsum[8];
#pragma unroll
  for (int q = 0; q < 8; ++q) {
    float s = 0.f;
#pragma unroll
    for (int k = 0; k < 8; ++k) {
      float p = exp2f((float)((int)mrow[q] - (int)acc[q][k]) * KFQ);
      pv[q][k] = p;
      s += p;
    }
#pragma unroll
    for (int off = 32; off; off >>= 1) s += __shfl_xor(s, off, 64);
    rsum[q] = s;
  }
  if (lane == 0) {
#pragma unroll
    for (int q = 0; q < 8; ++q) redf[wid][q] = rsum[q];
  }
  __syncthreads();
#pragma unroll
  for (int q = 0; q < 8; ++q)
    rsum[q] = (redf[0][q] + redf[1][q]) + (redf[2][q] + redf[3][q]);

  // normalized probs -> global attn (fp32) + Pstage (fp16, wave-local region)
#pragma unroll
  for (int q = 0; q < 8; ++q) {
    float inv = 1.0f / rsum[q];
    f4 p0, p1;
    h8_t hp;
#pragma unroll
    for (int i = 0; i < 4; ++i) {
      p0[i] = pv[q][i] * inv;
      p1[i] = pv[q][4 + i] * inv;
      hp[i] = (half_t)p0[i];
      hp[4 + i] = (half_t)p1[i];
    }
    size_t row = (size_t)(bh * LQ + q0 + q) * LK + t * 8;
    ((f4*)(attn + row))[0] = p0;
    ((f4*)(attn + row))[1] = p1;
    *(h8_t*)(Pst + q * PSTR + t * 8) = hp;  // lane-contiguous b128 write
  }
  // NOTE: each wave reads back only columns [wid*512, wid*512+512) of Pst,
  // written by its own lanes -> same-wave DS ordering, no barrier needed here.

  // PV: A-frag rows m>=8 duplicate rows m&7 (their C rows are discarded)
  f4 cfr[4];
#pragma unroll
  for (int nt = 0; nt < 4; ++nt) cfr[nt] = (f4){0.f, 0.f, 0.f, 0.f};
  const half_t* vf = Vfrag + (size_t)bh * (HD * LK);
#pragma unroll 2
  for (int c = 0; c < 16; ++c) {
    int kc = wid * 16 + c;
    h8_t af = *(const h8_t*)(Pst + (m & 7) * PSTR + kc * 32 + quad * 8);
#pragma unroll
    for (int nt = 0; nt < 4; ++nt) {
      h8_t bf = *(const h8_t*)(vf + (size_t)((kc * 4 + nt) * 64 + lane) * 8);
      cfr[nt] = __builtin_amdgcn_mfma_f32_16x16x32_f16(af, bf, cfr[nt], 0, 0, 0);
    }
  }

  __syncthreads();  // all waves done reading Pst before Cred overlays it
  if (quad < 2) {   // valid C rows 0..7 (row = quad*4 + r)
#pragma unroll
    for (int nt = 0; nt < 4; ++nt)
#pragma unroll
      for (int r = 0; r < 4; ++r)
        Cred[((wid * 8 + quad * 4 + r) * 64) + nt * 16 + m] = cfr[nt][r];
  }
  __syncthreads();

  {  // cross-wave sum + store: thread -> (q = t>>5, d pair = (t&31)*2)
    int q = t >> 5, d0 = (t & 31) * 2;
    float s0 = 0.f, s1 = 0.f;
#pragma unroll
    for (int w = 0; w < 4; ++w) {
      s0 += Cred[((w * 8 + q) * 64) + d0];
      s1 += Cred[((w * 8 + q) * 64) + d0 + 1];
    }
    float2 o = {s0, s1};
    *(float2*)(Xout + (size_t)(b * LQ + q0 + q) * HIDN + h * HD + d0) = o;
  }
}

// ---------- no-workspace fallbacks (R1-proven) ----------
__global__ __launch_bounds__(256, 2) void k_attn_slow(const float* __restrict__ Qin,
                                                      const float* __restrict__ Kin,
                                                      const float* __restrict__ diag,
                                                      float* __restrict__ attn) {
  int bid = blockIdx.x;
  int qt = bid & 15, bh = bid >> 4;
  int b = bh >> 4, h = bh & 15;
  int q0 = qt * 16, t = threadIdx.x;
  __shared__ float Qs[16][64];
  __shared__ float Dg[64];
  __shared__ float red[4][16];
  {
    int q = t >> 4;
    const f4* src = (const f4*)(Qin + (size_t)(b * LQ + q0 + q) * HIDN + h * HD);
    ((f4*)Qs[q])[t & 15] = src[t & 15];
  }
  if (t < 64) Dg[t] = diag[h * HD + t];
  __syncthreads();
  float acc[16][8];
#pragma unroll
  for (int q = 0; q < 16; ++q)
#pragma unroll
    for (int j = 0; j < 8; ++j) acc[q][j] = 0.f;
  const float* kfp = Kin + (size_t)(b * LK + t * 8) * HIDN + h * HD;
  for (int d = 0; d < 64; ++d) {
    float dgd = Dg[d];
    float kd[8];
#pragma unroll
    for (int j = 0; j < 8; ++j) kd[j] = kfp[(size_t)j * HIDN + d];
#pragma unroll
    for (int j = 0; j < 8; ++j) {
      float kv = kd[j];
#pragma unroll
      for (int q = 0; q < 16; ++q)
        acc[q][j] = fmaf(dgd, fabsf(kv - Qs[q][d]), acc[q][j]);
    }
  }
  int lane = t & 63, wid = t >> 6;
  float mrow[16];
#pragma unroll
  for (int q = 0; q < 16; ++q) {
    float mm = acc[q][0];
#pragma unroll
    for (int j = 1; j < 8; ++j) mm = fminf(mm, acc[q][j]);
#pragma unroll
    for (int off = 32; off; off >>= 1) mm = fminf(mm, __shfl_xor(mm, off, 64));
    mrow[q] = mm;
  }
  if (lane == 0)
#pragma unroll
    for (int q = 0; q < 16; ++q) red[wid][q] = mrow[q];
  __syncthreads();
#pragma unroll
  for (int q = 0; q < 16; ++q)
    mrow[q] = fminf(fminf(red[0][q], red[1][q]), fminf(red[2][q], red[3][q]));
  __syncthreads();
  float rsum[16];
#pragma unroll
  for (int q = 0; q < 16; ++q) {
    float s = 0.f;
#pragma unroll
    for (int j = 0; j < 8; ++j) {
      float p = exp2f((mrow[q] - acc[q][j]) * KF);
      acc[q][j] = p;
      s += p;
    }
#pragma unroll
    for (int off = 32; off; off >>= 1) s += __shfl_xor(s, off, 64);
    rsum[q] = s;
  }
  if (lane == 0)
#pragma unroll
    for (int q = 0; q < 16; ++q) red[wid][q] = rsum[q];
  __syncthreads();
#pragma unroll
  for (int q = 0; q < 16; ++q)
    rsum[q] = (red[0][q] + red[1][q]) + (red[2][q] + red[3][q]);
#pragma unroll
  for (int q = 0; q < 16; ++q) {
    float inv = 1.0f / rsum[q];
    f4 p0, p1;
#pragma unroll
    for (int i = 0; i < 4; ++i) { p0[i] = acc[q][i] * inv; p1[i] = acc[q][4 + i] * inv; }
    float* op = attn + ((size_t)(bh * LQ + q0 + q)) * LK + t * 8;
    ((f4*)op)[0] = p0;
    ((f4*)op)[1] = p1;
  }
}

__global__ __launch_bounds__(256) void k_pv_old(const float* __restrict__ P,
                                                const float* __restrict__ Vin,
                                                float* __restrict__ Xout) {
  int bid = blockIdx.x;
  int qt = bid & 3, bh = bid >> 2;
  int b = bh >> 4, h = bh & 15;
  int q0 = qt * 64;
  int t = threadIdx.x, lane = t & 63, wid = t >> 6;
  int m = lane & 15, quad = lane >> 4;
  __shared__ half_t Vts[64 * 256];
  f4 cfr[4];
#pragma unroll
  for (int nt = 0; nt < 4; ++nt) cfr[nt] = (f4){0.f, 0.f, 0.f, 0.f};
  int qrow = q0 + wid * 16 + m;
  const float* pbase = P + ((size_t)(bh * LQ + qrow)) * LK + quad * 8;
  for (int kb = 0; kb < 8; ++kb) {
    {
      int d = wid * 16 + (lane & 15);
      int kg = lane >> 4;
      const float* vp = Vin + (size_t)(b * LK + kb * 256) * HIDN + h * HD + d;
#pragma unroll
      for (int i = 0; i < 32; ++i) {
        int kl = i * 8 + kg * 2;
        float v0 = vp[(size_t)kl * HIDN];
        float v1 = vp[(size_t)(kl + 1) * HIDN];
        int addr = d * 256 + ((((kl >> 3) ^ (d & 7)) << 3) | (kl & 7));
        Vts[addr] = (half_t)v0;
        Vts[addr + 1] = (half_t)v1;
      }
    }
    __syncthreads();
#pragma unroll
    for (int ks = 0; ks < 8; ++ks) {
      const float* pp = pbase + kb * 256 + ks * 32;
      f4 a0 = ((const f4*)pp)[0];
      f4 a1 = ((const f4*)pp)[1];
      h8_t af;
#pragma unroll
      for (int i = 0; i < 4; ++i) { af[i] = (half_t)a0[i]; af[4 + i] = (half_t)a1[i]; }
      int koff = ks * 32 + quad * 8;
#pragma unroll
      for (int nt = 0; nt < 4; ++nt) {
        int n = nt * 16 + m;
        int vaddr = n * 256 + ((((koff >> 3) ^ (n & 7)) << 3));
        h8_t bf = *(const h8_t*)&Vts[vaddr];
        cfr[nt] = __builtin_amdgcn_mfma_f32_16x16x32_f16(af, bf, cfr[nt], 0, 0, 0);
      }
    }
    __syncthreads();
  }
#pragma unroll
  for (int nt = 0; nt < 4; ++nt)
#pragma unroll
    for (int r = 0; r < 4; ++r) {
      int row = quad * 4 + r;
      int q = q0 + wid * 16 + row;
      Xout[(size_t)(b * LQ + q) * HIDN + h * HD + nt * 16 + m] = cfr[nt][r];
    }
}

extern "C" void kernel_launch(void* const* d_in, const int* in_sizes, int n_in,
                              void* d_out, int out_size, void* d_ws, size_t ws_size,
                              hipStream_t stream) {
  const float* Q = (const float*)d_in[0];
  const float* K = (const float*)d_in[1];
  const float* V = (const float*)d_in[2];
  const float* dg = (const float*)d_in[3];
  float* out = (float*)d_out;                  // [B,LQ,HID]
  float* attn = out + (size_t)NB * LQ * HIDN;  // [B,H,LQ,LK]

  size_t ktB = (size_t)NB * NH * 32 * LK * 4;  // 16.78 MB Ktq
  size_t vfB = (size_t)NB * NH * HD * LK * 2;  // 16.78 MB Vfrag
  char* wsb = (char*)d_ws;
  uint32_t* Ktq = (uint32_t*)wsb;
  half_t* Vfrag = (half_t*)(wsb + ktB);

  if (ws_size >= ktB + vfB) {
    k_prep4<<<NB * NH * 32 * 2, 256, 0, stream>>>(K, V, dg, Ktq, Vfrag);
    k_fused<<<NB * NH * 32, 256, 0, stream>>>(Q, Ktq, dg, Vfrag, attn, out);
  } else {
    k_attn_slow<<<NB * NH * 16, 256, 0, stream>>>(Q, K, dg, attn);
    k_pv_old<<<NB * NH * 4, 256, 0, stream>>>(attn, V, out);
  }
}